// Round 8
// baseline (112.291 us; speedup 1.0000x reference)
//
#include <hip/hip_runtime.h>
#include <hip/hip_fp16.h>

// GraphConv on MI355X — single fused kernel, round 8.
// vs round 7: ALL weight matrices staged through LDS (transposed, fp16) via
// coalesced float4 loads; every MFMA B-fragment is a single ds_read_b128.
// Scalar column-strided global loads (~400/thread at ~200cy L2 latency each
// batch) were the hidden serial cost of rounds 4-7.
//  * WB buffer: W1T both-enc (stride 40) -> reused for W2T per-enc (stride 72).
//  * Decoder weights staged into dead PlH after the main loop (all threads),
//    decoder itself still wave-0 MFMA.
//  * LDS 39.8 KB -> 4 blocks/CU, grid 1024 = 256 CU x 4 fully co-resident.

typedef _Float16 hf;
typedef __attribute__((ext_vector_type(8))) _Float16 v8hf;  // 4 VGPRs, MFMA A/B
typedef __attribute__((ext_vector_type(4))) float fv4;      // MFMA accumulator

union ABh { v8hf v; __half2 h[4]; };

// grid = 128 b * 8 recv-groups, 256 threads (4 waves).
__global__ __launch_bounds__(256, 4) void fused_kernel(
    const float* __restrict__ ns, const float* __restrict__ et,
    const float* __restrict__ e0w1, const float* __restrict__ e0b1,
    const float* __restrict__ e0w2, const float* __restrict__ e0b2,
    const float* __restrict__ e1w1, const float* __restrict__ e1b1,
    const float* __restrict__ e1w2, const float* __restrict__ e1b2,
    const float* __restrict__ ndw1, const float* __restrict__ ndb1,
    const float* __restrict__ ndw2, const float* __restrict__ ndb2,
    float* __restrict__ out)
{
  __shared__ __align__(16) _Float16 PlH[2*64*72];   // 18432 B  P partials; later ndw1T/ndw2T
  __shared__ __align__(16) _Float16 QbH[2*8*64];    //  2048 B  Q + b1
  __shared__ float ETl[2*8*64];                     //  4096 B  edge weights (fp32)
  // XDH rows 0-7: XD = [ns(16)|msg(64)|0(16)] stride 104; rows 8-23: HD2
  __shared__ __align__(16) _Float16 XDH[24*104];    //  4992 B
  __shared__ __align__(16) _Float16 WB[2*64*40 + 16]; // 10272 B weight staging
                                                    // total 39840 B
  _Float16* XD  = XDH;
  _Float16* HD2 = XDH + 8*104;

  int t = threadIdx.x;
  int b = blockIdx.x >> 3, rg = blockIdx.x & 7, r0 = rg*8;
  int w = t >> 6, lane = t & 63, quad = lane >> 4, col = lane & 15;

  const __half2 z2 = __float22half2_rn(make_float2(0.f, 0.f));
  const v8hf zero8 = {};

  // ======== early global loads (held in regs until after barrier #2) ========
  float xnv = 0.f;
  if (t < 128) xnv = ns[(b*64 + r0 + (t >> 4))*16 + (t & 15)];
  float ev0[2], ev1[2];
#pragma unroll
  for (int i = 0; i < 2; ++i) {
    int idx = i*256 + t;                  // 0..511 -> (s, rl)
    int s = idx >> 3, rl = idx & 7;
    int r = r0 + rl;
    float v0 = 0.f, v1 = 0.f;
    if (s != r) {
      int pos = r - (r > s ? 1 : 0);
      const float* base = et + (b*4032 + s*63 + pos)*3;
      v0 = base[1]; v1 = base[2];
    }
    ev0[i] = v0; ev1[i] = v1;
  }

  // ======== stage W1T (both enc, transposed, fp16): W1T[enc][h][k], stride 40
#pragma unroll
  for (int it = 0; it < 4; ++it) {
    int idx = it*256 + t;                 // 0..1023 float4s
    int enc = idx >> 9, rem = idx & 511;
    int k = rem >> 4, h0 = (rem & 15)*4;
    const float* w1 = enc ? e1w1 : e0w1;
    float4 v = *(const float4*)(w1 + k*64 + h0);
    hf* dst = WB + enc*2560 + h0*40 + k;
    dst[0*40] = (hf)v.x; dst[1*40] = (hf)v.y; dst[2*40] = (hf)v.z; dst[3*40] = (hf)v.w;
  }
  // zero pad cols k=32..39 of every row (+tail) — garbage LDS could be NaN
#pragma unroll
  for (int d = 0; d < 4; ++d) {
    int z = t*4 + d;                      // 0..1023
    WB[(z >> 3)*40 + 32 + (z & 7)] = (hf)0.f;
  }
  if (t < 16) WB[5120 + t] = (hf)0.f;
  __syncthreads();                        // B#1

  // ======== P and Q via MFMA: node-tile @ W1 (64x64x16, K padded to 32) ====
  // wave w owns nodes w*16..w*16+15. A[m=col][k=quad*8+j] = ns[node][k], k<16.
  {
    ABh a;
    if (quad < 2) {
      const float* xr = ns + (b*64 + w*16 + col)*16 + quad*8;
      float4 x0 = *(const float4*)xr;
      float4 x1 = *(const float4*)(xr + 4);
      a.h[0] = __float22half2_rn(make_float2(x0.x, x0.y));
      a.h[1] = __float22half2_rn(make_float2(x0.z, x0.w));
      a.h[2] = __float22half2_rn(make_float2(x1.x, x1.y));
      a.h[3] = __float22half2_rn(make_float2(x1.z, x1.w));
    } else {
      a.h[0] = a.h[1] = a.h[2] = a.h[3] = z2;
    }
    bool qwave = (w == (rg >> 1));        // this wave's tile contains r0..r0+7
#pragma unroll 1
    for (int enc = 0; enc < 2; ++enc) {
      const float* b1 = enc ? e1b1 : e0b1;
#pragma unroll
      for (int ht = 0; ht < 4; ++ht) {
        int cc = ht*16 + col;
        // B[k][cc] = W1[k][cc] -> W1T row cc, k=quad*8.. (A zero for k>=16)
        v8hf bb = *(const v8hf*)(WB + enc*2560 + cc*40 + quad*8);
        fv4 acc = {0.f, 0.f, 0.f, 0.f};
        acc = __builtin_amdgcn_mfma_f32_16x16x32_f16(a.v, bb, acc, 0, 0, 0);
        hf* pd = PlH + enc*4608 + (w*16 + quad*4)*72 + cc;
        pd[0*72] = (hf)acc[0];
        pd[1*72] = (hf)acc[1];
        pd[2*72] = (hf)acc[2];
        pd[3*72] = (hf)acc[3];
      }
      if (qwave) {                        // Q: W1 bottom rows 16..31 -> offset +16
#pragma unroll
        for (int ht = 0; ht < 4; ++ht) {
          int cc = ht*16 + col;
          v8hf bb = *(const v8hf*)(WB + enc*2560 + cc*40 + 16 + quad*8);
          fv4 acc = {0.f, 0.f, 0.f, 0.f};
          acc = __builtin_amdgcn_mfma_f32_16x16x32_f16(a.v, bb, acc, 0, 0, 0);
          float b1v = b1[cc];
#pragma unroll
          for (int rr = 0; rr < 4; ++rr) {
            int local = quad*4 + rr;      // node = w*16 + local
            if ((local >> 3) == (rg & 1))
              QbH[enc*512 + (local & 7)*64 + cc] = (hf)(acc[rr] + b1v);
          }
        }
      }
    }
  }
  __syncthreads();                        // B#2 (W1T reads + P/Q writes done)

  // ======== stage W2T enc0 (transposed fp16, stride 72) + XD/ET to LDS ====
#pragma unroll
  for (int it = 0; it < 4; ++it) {
    int idx = it*256 + t;                 // 0..1023
    int k = idx >> 4, n0 = (idx & 15)*4;
    float4 v = *(const float4*)(e0w2 + k*64 + n0);
    hf* dst = WB + n0*72 + k;
    dst[0*72] = (hf)v.x; dst[1*72] = (hf)v.y; dst[2*72] = (hf)v.z; dst[3*72] = (hf)v.w;
  }
  if (t < 128) {
    int rl = t >> 4, k = t & 15;
    XD[rl*104 + k] = (hf)xnv;             // ns part
    XD[rl*104 + 80 + k] = (hf)0.f;        // zero pad cols 80..95
  }
#pragma unroll
  for (int i = 0; i < 2; ++i) {
    int idx = i*256 + t;
    int s = idx >> 3, rl = idx & 7;
    ETl[rl*64 + s] = ev0[i];
    ETl[512 + rl*64 + s] = ev1[i];
  }
  __syncthreads();                        // B#3

  // ======== main loop: h2 = relu(h1 @ W2 + b2), et-weighted sum ========
  float msgacc[2][4] = {{0.f,0.f,0.f,0.f},{0.f,0.f,0.f,0.f}};

#pragma unroll 1
  for (int enc = 0; enc < 2; ++enc) {
    if (enc == 1) {
      __syncthreads();                    // B#4 (enc0 W2T reads done)
#pragma unroll
      for (int it = 0; it < 4; ++it) {
        int idx = it*256 + t;
        int k = idx >> 4, n0 = (idx & 15)*4;
        float4 v = *(const float4*)(e1w2 + k*64 + n0);
        hf* dst = WB + n0*72 + k;
        dst[0*72] = (hf)v.x; dst[1*72] = (hf)v.y; dst[2*72] = (hf)v.z; dst[3*72] = (hf)v.w;
      }
      __syncthreads();                    // B#5
    }
    const float* b2 = enc ? e1b2 : e0b2;
    v8hf bfr[4][2];
    float b2v[4];
#pragma unroll
    for (int nt = 0; nt < 4; ++nt) {      // B-frags: one ds_read_b128 each
#pragma unroll
      for (int kk = 0; kk < 2; ++kk)
        bfr[nt][kk] = *(const v8hf*)(WB + (nt*16 + col)*72 + kk*32 + quad*8);
      b2v[nt] = b2[nt*16 + col];
    }
#pragma unroll 1
    for (int rli = 0; rli < 2; ++rli) {
      int rl = w*2 + rli;                 // this wave owns receivers 2w, 2w+1
      const hf* qrow = QbH + (enc*8 + rl)*64;
      v8hf q0 = *(const v8hf*)(qrow + quad*8);
      v8hf q1 = *(const v8hf*)(qrow + 32 + quad*8);
      const float* etrow = ETl + (enc*8 + rl)*64;
#pragma unroll 2
      for (int st = 0; st < 4; ++st) {
        const hf* prow = PlH + enc*4608 + (st*16 + col)*72 + quad*8;
        v8hf p0 = *(const v8hf*)prow;
        v8hf p1 = *(const v8hf*)(prow + 32);
        v8hf s0 = __builtin_elementwise_max(p0 + q0, zero8);
        v8hf s1 = __builtin_elementwise_max(p1 + q1, zero8);
        float4 etv = *(const float4*)(etrow + st*16 + quad*4);
#pragma unroll
        for (int nt = 0; nt < 4; ++nt) {
          fv4 acc = {b2v[nt], b2v[nt], b2v[nt], b2v[nt]};
          acc = __builtin_amdgcn_mfma_f32_16x16x32_f16(s0, bfr[nt][0], acc, 0, 0, 0);
          acc = __builtin_amdgcn_mfma_f32_16x16x32_f16(s1, bfr[nt][1], acc, 0, 0, 0);
          float m = msgacc[rli][nt];
          m += etv.x * fmaxf(acc[0], 0.f);
          m += etv.y * fmaxf(acc[1], 0.f);
          m += etv.z * fmaxf(acc[2], 0.f);
          m += etv.w * fmaxf(acc[3], 0.f);
          msgacc[rli][nt] = m;
        }
      }
    }
  }
  // quad reduction over senders -> XD msg part (fp16)
#pragma unroll
  for (int rli = 0; rli < 2; ++rli) {
#pragma unroll
    for (int nt = 0; nt < 4; ++nt) {
      float v = msgacc[rli][nt];
      v += __shfl_xor(v, 16);
      v += __shfl_xor(v, 32);
      if (lane < 16) XD[(w*2 + rli)*104 + 16 + nt*16 + lane] = (hf)v;
    }
  }
  __syncthreads();                        // B#6 (msg written, PlH reads done)

  // ======== stage decoder weights into dead PlH (all threads) ========
  // ndw1T[n][k] stride 104 (k<80 data, 80..95 zero); ndw2T[o][k] stride 72 @ +6656
#pragma unroll
  for (int it = 0; it < 5; ++it) {
    int idx = it*256 + t;                 // 0..1279
    int k = idx >> 4, n0 = (idx & 15)*4;
    float4 v = *(const float4*)(ndw1 + k*64 + n0);
    hf* dst = PlH + n0*104 + k;
    dst[0*104] = (hf)v.x; dst[1*104] = (hf)v.y; dst[2*104] = (hf)v.z; dst[3*104] = (hf)v.w;
  }
#pragma unroll
  for (int d = 0; d < 4; ++d) {
    int z = t*4 + d;                      // 0..1023: zero k=80..95, n=0..63
    PlH[(z >> 4)*104 + 80 + (z & 15)] = (hf)0.f;
  }
  {
    int k = t >> 2, o0 = (t & 3)*4;       // 256 float4s, 1/thread
    float4 v = *(const float4*)(ndw2 + k*16 + o0);
    hf* nd2 = PlH + 6656;
    nd2[(o0+0)*72 + k] = (hf)v.x; nd2[(o0+1)*72 + k] = (hf)v.y;
    nd2[(o0+2)*72 + k] = (hf)v.z; nd2[(o0+3)*72 + k] = (hf)v.w;
  }
  __syncthreads();                        // B#7

  // ======== decoder via MFMA, wave 0 only ========
  if (w == 0) {
    ABh xa[3];
    const hf* xrow = XD + col*104;        // rows 8-15 garbage -> discarded C rows
#pragma unroll
    for (int kk = 0; kk < 3; ++kk) xa[kk].v = *(const v8hf*)(xrow + kk*32 + quad*8);
#pragma unroll
    for (int ht = 0; ht < 4; ++ht) {
      int cc = ht*16 + col;
      float bias = ndb1[cc];
      fv4 acc = {bias, bias, bias, bias};
#pragma unroll
      for (int kk = 0; kk < 3; ++kk) {
        v8hf bb = *(const v8hf*)(PlH + cc*104 + kk*32 + quad*8);
        acc = __builtin_amdgcn_mfma_f32_16x16x32_f16(xa[kk].v, bb, acc, 0, 0, 0);
      }
      if (quad < 2) {
#pragma unroll
        for (int rr = 0; rr < 4; ++rr)
          HD2[(quad*4 + rr)*104 + cc] = (hf)fmaxf(acc[rr], 0.f);
      }
    }
    // layer2 (same-wave LDS write->read, program order)
    const hf* hrow = HD2 + col*104;
    v8hf ha0 = *(const v8hf*)(hrow + quad*8);
    v8hf ha1 = *(const v8hf*)(hrow + 32 + quad*8);
    const hf* nd2 = PlH + 6656;
    v8hf b20 = *(const v8hf*)(nd2 + col*72 + quad*8);
    v8hf b21 = *(const v8hf*)(nd2 + col*72 + 32 + quad*8);
    float bias2 = ndb2[col];
    fv4 acc2 = {bias2, bias2, bias2, bias2};
    acc2 = __builtin_amdgcn_mfma_f32_16x16x32_f16(ha0, b20, acc2, 0, 0, 0);
    acc2 = __builtin_amdgcn_mfma_f32_16x16x32_f16(ha1, b21, acc2, 0, 0, 0);
    if (quad < 2) {
#pragma unroll
      for (int rr = 0; rr < 4; ++rr) {
        int rl = quad*4 + rr;
        out[(b*64 + r0 + rl)*16 + col] = fmaxf(acc2[rr], 0.f);
      }
    }
  }
}

extern "C" void kernel_launch(void* const* d_in, const int* in_sizes, int n_in,
                              void* d_out, int out_size, void* d_ws, size_t ws_size,
                              hipStream_t stream) {
  const float* ns   = (const float*)d_in[0];
  const float* et   = (const float*)d_in[1];
  const float* e0w1 = (const float*)d_in[2];
  const float* e0b1 = (const float*)d_in[3];
  const float* e0w2 = (const float*)d_in[4];
  const float* e0b2 = (const float*)d_in[5];
  const float* e1w1 = (const float*)d_in[6];
  const float* e1b1 = (const float*)d_in[7];
  const float* e1w2 = (const float*)d_in[8];
  const float* e1b2 = (const float*)d_in[9];
  const float* ndw1 = (const float*)d_in[10];
  const float* ndb1 = (const float*)d_in[11];
  const float* ndw2 = (const float*)d_in[12];
  const float* ndb2 = (const float*)d_in[13];

  fused_kernel<<<1024, 256, 0, stream>>>(ns, et,
                                         e0w1, e0b1, e0w2, e0b2,
                                         e1w1, e1b1, e1w2, e1b2,
                                         ndw1, ndb1, ndw2, ndb2,
                                         (float*)d_out);
}